// Round 14
// baseline (718.124 us; speedup 1.0000x reference)
//
#include <hip/hip_runtime.h>
#include <hip/hip_bf16.h>
#include <hip/hip_fp16.h>

#define HID 128

typedef _Float16 f16x8 __attribute__((ext_vector_type(8)));
typedef float f32x4 __attribute__((ext_vector_type(4)));

// ---------------- zero ----------------
__global__ __launch_bounds__(256)
void zero_int_kernel(int* __restrict__ p, long n) {
    long i = (long)blockIdx.x * 256 + threadIdx.x;
    long stride = (long)gridDim.x * 256;
    for (; i < n; i += stride) p[i] = 0;
}

// ---------------- degree count (int) ----------------
__global__ __launch_bounds__(256)
void count_deg_kernel(const int* __restrict__ ei, int* __restrict__ cnt, long E) {
    long e = (long)blockIdx.x * 256 + threadIdx.x;
    if (e < E) atomicAdd(&cnt[ei[E + e]], 1);
}

__global__ __launch_bounds__(256)
void dis_kernel(const int* __restrict__ cnt, float* __restrict__ dis, int N) {
    int i = blockIdx.x * 256 + threadIdx.x;
    if (i < N) dis[i] = rsqrtf(1.0f + (float)cnt[i]);   // +1 self loop
}

// ---------------- exclusive scan (3-phase) ----------------
__global__ __launch_bounds__(256)
void scan1_kernel(const int* __restrict__ cnt, int* __restrict__ off,
                  int* __restrict__ bsum, int N) {
    __shared__ int sh[256];
    int i = blockIdx.x * 256 + threadIdx.x;
    int v = (i < N) ? cnt[i] : 0;
    sh[threadIdx.x] = v;
    __syncthreads();
    for (int o = 1; o < 256; o <<= 1) {
        int t = 0;
        if (threadIdx.x >= o) t = sh[threadIdx.x - o];
        __syncthreads();
        if (threadIdx.x >= o) sh[threadIdx.x] += t;
        __syncthreads();
    }
    if (i < N) off[i] = sh[threadIdx.x] - v;
    if (threadIdx.x == 255) bsum[blockIdx.x] = sh[255];
}

__global__ __launch_bounds__(1024)
void scan2_kernel(int* __restrict__ bsum, int nb) {
    __shared__ int sh[1024];
    int t = threadIdx.x;
    int v = (t < nb) ? bsum[t] : 0;
    sh[t] = v;
    __syncthreads();
    for (int o = 1; o < 1024; o <<= 1) {
        int u = 0;
        if (t >= o) u = sh[t - o];
        __syncthreads();
        if (t >= o) sh[t] += u;
        __syncthreads();
    }
    if (t < nb) bsum[t] = sh[t] - v;
}

__global__ __launch_bounds__(256)
void scan3_kernel(int* __restrict__ off, const int* __restrict__ bsum, int N, int E) {
    int i = blockIdx.x * 256 + threadIdx.x;
    if (i < N) off[i] += bsum[blockIdx.x];
    if (i == 0) off[N] = E;
}

// ---------------- CSR fill (src index only — weight folded into M') --------
__global__ __launch_bounds__(256)
void fill_kernel(const int* __restrict__ ei, const int* __restrict__ off,
                 int* __restrict__ cnt, int* __restrict__ csr_src, long E) {
    long e = (long)blockIdx.x * 256 + threadIdx.x;
    if (e >= E) return;
    int s = ei[e], d = ei[E + e];
    int pos = off[d] + atomicAdd(&cnt[d], 1);
    csr_src[pos] = s;
}

// ---------------- build h193 fp16 [N,224] (zero-padded) ----------------
__global__ __launch_bounds__(256)
void conv193_kernel(const float* __restrict__ x, const float* __restrict__ pk,
                    const float* __restrict__ pp, __half* __restrict__ h16, int N)
{
    long i = (long)blockIdx.x * 256 + threadIdx.x;   // over N*56 col-quads
    if (i >= (long)N * 56) return;
    int r = (int)(i / 56), q = (int)(i - (long)r * 56);
    int c = q * 4;
    float4 v;
    if (c < 128)       v = *reinterpret_cast<const float4*>(x  + (long)r * 128 + c);
    else if (c < 192)  v = *reinterpret_cast<const float4*>(pk + (long)r * 64 + (c - 128));
    else if (c == 192) v = make_float4(pp[r], 0.f, 0.f, 0.f);
    else               v = make_float4(0.f, 0.f, 0.f, 0.f);
    __half h4[4] = {__float2half(v.x), __float2half(v.y), __float2half(v.z), __float2half(v.w)};
    *reinterpret_cast<uint2*>(h16 + (long)r * 224 + c) = *reinterpret_cast<uint2*>(h4);
}

// ------- transpose weight: WT[c][k] = W[k][c], fp16, zero-pad k>=K ----------
// W is [K, C] row-major; WT is [C, KP].
__global__ __launch_bounds__(256)
void transpose_w_kernel(const float* __restrict__ W, __half* __restrict__ WT,
                        int K, int KP, int C)
{
    int i = blockIdx.x * 256 + threadIdx.x;
    if (i >= C * KP) return;
    int c = i / KP, k = i - c * KP;
    WT[i] = (k < K) ? __float2half(W[(long)k * C + c]) : __half(0.f);
}

// ======== MFMA linear: out[N,128] = A16[N,KP] @ W[KP,128], fp16 out ========
// 128x128 tile, 4 waves (2x2), wave = 4x4 frags of 16x16x32_f16.
// OUTMODE 0: write fp16 of acc * dis[row]  (pre-scaled message M').
// OUTMODE 1: write fp16 sigmoid(acc+bias)  (gate).
template<int KP, int OUTMODE>
__global__ __launch_bounds__(256)
void mfma_lin_kernel(const __half* __restrict__ A16, const __half* __restrict__ WT,
                     const float* __restrict__ bias, const float* __restrict__ dis,
                     __half* __restrict__ outp, int N)
{
    constexpr int NK = KP / 32;
    __shared__ __half Al[128 * 40];
    __shared__ __half Bl[128 * 40];
    int t = threadIdx.x;
    int w = t >> 6, lane = t & 63;
    int wr = (w & 1) * 64, wc = (w >> 1) * 64;
    int row0 = blockIdx.x * 128;
    int lrow = lane & 15, lk = (lane >> 4) * 8;

    f32x4 acc[4][4];
    #pragma unroll
    for (int i = 0; i < 4; ++i)
        #pragma unroll
        for (int j = 0; j < 4; ++j)
            #pragma unroll
            for (int q = 0; q < 4; ++q) acc[i][j][q] = 0.f;

    int sr = t >> 2, sp = t & 3;
    for (int ks = 0; ks < NK; ++ks) {
        if (ks) __syncthreads();
        {
            int rr  = min(row0 + sr, N - 1);
            int rr2 = min(row0 + sr + 64, N - 1);
            *reinterpret_cast<uint4*>(Al + sr * 40 + sp * 8) =
                *reinterpret_cast<const uint4*>(A16 + (long)rr * KP + ks * 32 + sp * 8);
            *reinterpret_cast<uint4*>(Al + (sr + 64) * 40 + sp * 8) =
                *reinterpret_cast<const uint4*>(A16 + (long)rr2 * KP + ks * 32 + sp * 8);
            *reinterpret_cast<uint4*>(Bl + sr * 40 + sp * 8) =
                *reinterpret_cast<const uint4*>(WT + (long)sr * KP + ks * 32 + sp * 8);
            *reinterpret_cast<uint4*>(Bl + (sr + 64) * 40 + sp * 8) =
                *reinterpret_cast<const uint4*>(WT + (long)(sr + 64) * KP + ks * 32 + sp * 8);
        }
        __syncthreads();
        f16x8 af[4], bf[4];
        #pragma unroll
        for (int i = 0; i < 4; ++i) {
            af[i] = *reinterpret_cast<const f16x8*>(Al + (wr + i * 16 + lrow) * 40 + lk);
            bf[i] = *reinterpret_cast<const f16x8*>(Bl + (wc + i * 16 + lrow) * 40 + lk);
        }
        #pragma unroll
        for (int i = 0; i < 4; ++i)
            #pragma unroll
            for (int j = 0; j < 4; ++j)
                acc[i][j] = __builtin_amdgcn_mfma_f32_16x16x32_f16(af[i], bf[j], acc[i][j], 0, 0, 0);
    }

    int orow_b = (lane >> 4) * 4;
    #pragma unroll
    for (int i = 0; i < 4; ++i) {
        #pragma unroll
        for (int j = 0; j < 4; ++j) {
            int col = wc + j * 16 + lrow;
            #pragma unroll
            for (int q = 0; q < 4; ++q) {
                int row = row0 + wr + i * 16 + orow_b + q;
                if (row >= N) continue;
                float v = acc[i][j][q];
                if (OUTMODE == 0) {
                    v *= dis[row];                 // fold edge weight dis[src] into M'
                } else {
                    v += bias[col];
                    v = 1.f / (1.f + expf(-v));
                }
                outp[(long)row * HID + col] = __float2half(v);
            }
        }
    }
}

// ------------- fused: fp16 CSR gather (pre-scaled M') + LN + relu + post ----
// v = dis[r] * (sum_e M'[src[e]] + M'[r]) + bias      (M' = dis*m)
// MODE 0: hout[r] = relu(LN(v)) * hin[r]  (hin = gate, fp16)
// MODE 1: hout[r] = hin[r] + relu(LN(v))  (hin == hout = h, fp16)
template<int MODE>
__global__ __launch_bounds__(256)
void gcn16_kernel(const int* __restrict__ off, const int* __restrict__ src,
                  const float* __restrict__ dis,
                  const __half* __restrict__ m16, const float* __restrict__ bias,
                  const float* __restrict__ g, const float* __restrict__ be,
                  const __half* __restrict__ hin, __half* __restrict__ hout, int N)
{
    int wave = threadIdx.x >> 6, lane = threadIdx.x & 63;
    int r = blockIdx.x * 4 + wave;
    if (r >= N) return;
    int beg = off[r], end = off[r + 1];
    float dr = dis[r];
    int c2 = lane << 1;
    float sx0 = 0.f, sy0 = 0.f, sx1 = 0.f, sy1 = 0.f;
    float sx2 = 0.f, sy2 = 0.f, sx3 = 0.f, sy3 = 0.f;
    int e = beg;
    for (; e + 8 <= end; e += 8) {
        int s0 = src[e],     s1 = src[e + 1], s2 = src[e + 2], s3 = src[e + 3];
        int s4 = src[e + 4], s5 = src[e + 5], s6 = src[e + 6], s7 = src[e + 7];
        __half2 h0 = *reinterpret_cast<const __half2*>(m16 + (long)s0 * HID + c2);
        __half2 h1 = *reinterpret_cast<const __half2*>(m16 + (long)s1 * HID + c2);
        __half2 h2 = *reinterpret_cast<const __half2*>(m16 + (long)s2 * HID + c2);
        __half2 h3 = *reinterpret_cast<const __half2*>(m16 + (long)s3 * HID + c2);
        __half2 h4 = *reinterpret_cast<const __half2*>(m16 + (long)s4 * HID + c2);
        __half2 h5 = *reinterpret_cast<const __half2*>(m16 + (long)s5 * HID + c2);
        __half2 h6 = *reinterpret_cast<const __half2*>(m16 + (long)s6 * HID + c2);
        __half2 h7 = *reinterpret_cast<const __half2*>(m16 + (long)s7 * HID + c2);
        float2 f0 = __half22float2(h0), f1 = __half22float2(h1);
        float2 f2 = __half22float2(h2), f3 = __half22float2(h3);
        float2 f4 = __half22float2(h4), f5 = __half22float2(h5);
        float2 f6 = __half22float2(h6), f7 = __half22float2(h7);
        sx0 += f0.x + f4.x; sy0 += f0.y + f4.y;
        sx1 += f1.x + f5.x; sy1 += f1.y + f5.y;
        sx2 += f2.x + f6.x; sy2 += f2.y + f6.y;
        sx3 += f3.x + f7.x; sy3 += f3.y + f7.y;
    }
    for (; e < end; ++e) {
        int s0 = src[e];
        float2 f0 = __half22float2(*reinterpret_cast<const __half2*>(m16 + (long)s0 * HID + c2));
        sx0 += f0.x; sy0 += f0.y;
    }
    float2 ms = __half22float2(*reinterpret_cast<const __half2*>(m16 + (long)r * HID + c2));
    const float2 bi = *reinterpret_cast<const float2*>(bias + c2);
    float vx = dr * ((sx0 + sx1) + (sx2 + sx3) + ms.x) + bi.x;
    float vy = dr * ((sy0 + sy1) + (sy2 + sy3) + ms.y) + bi.y;
    float s = vx + vy;
    for (int o = 32; o; o >>= 1) s += __shfl_xor(s, o);
    float mean = s * (1.f / 128.f);
    float qx = vx - mean, qy = vy - mean;
    float q = qx * qx + qy * qy;
    for (int o = 32; o; o >>= 1) q += __shfl_xor(q, o);
    float rs = rsqrtf(q * (1.f / 128.f) + 1e-5f);
    const float2 gg = *reinterpret_cast<const float2*>(g + c2);
    const float2 bb = *reinterpret_cast<const float2*>(be + c2);
    float y0 = fmaxf(qx * rs * gg.x + bb.x, 0.f);
    float y1 = fmaxf(qy * rs * gg.y + bb.y, 0.f);
    float2 hv = __half22float2(*reinterpret_cast<const __half2*>(hin + (long)r * HID + c2));
    float2 o2;
    if (MODE == 0) { o2.x = y0 * hv.x; o2.y = y1 * hv.y; }
    else           { o2.x = hv.x + y0; o2.y = hv.y + y1; }
    *reinterpret_cast<__half2*>(hout + (long)r * HID + c2) = __float22half2_rn(o2);
}

// ======== MFMA head: out[r] = relu(h16@Wp1+bp1) @ Wp2 + bp2 ================
// 128 rows x 64 cols per block; 4 waves, each 32 rows; K=128.
__global__ __launch_bounds__(256)
void head3_kernel(const __half* __restrict__ h16, const __half* __restrict__ WTp1,
                  const float* __restrict__ bp1, const float* __restrict__ Wp2,
                  const float* __restrict__ bp2, float* __restrict__ out, int N)
{
    __shared__ __half Al[128 * 40];
    __shared__ __half Bl[64 * 40];
    int t = threadIdx.x;
    int w = t >> 6, lane = t & 63;
    int wr = w * 32;
    int row0 = blockIdx.x * 128;
    int lrow = lane & 15, lk = (lane >> 4) * 8;

    f32x4 acc[2][4];
    #pragma unroll
    for (int i = 0; i < 2; ++i)
        #pragma unroll
        for (int j = 0; j < 4; ++j)
            #pragma unroll
            for (int q = 0; q < 4; ++q) acc[i][j][q] = 0.f;

    int sr = t >> 2, sp = t & 3;
    for (int ks = 0; ks < 4; ++ks) {
        if (ks) __syncthreads();
        {
            int rr  = min(row0 + sr, N - 1);
            int rr2 = min(row0 + sr + 64, N - 1);
            *reinterpret_cast<uint4*>(Al + sr * 40 + sp * 8) =
                *reinterpret_cast<const uint4*>(h16 + (long)rr * HID + ks * 32 + sp * 8);
            *reinterpret_cast<uint4*>(Al + (sr + 64) * 40 + sp * 8) =
                *reinterpret_cast<const uint4*>(h16 + (long)rr2 * HID + ks * 32 + sp * 8);
            if (sr < 64)
                *reinterpret_cast<uint4*>(Bl + sr * 40 + sp * 8) =
                    *reinterpret_cast<const uint4*>(WTp1 + (long)sr * HID + ks * 32 + sp * 8);
        }
        __syncthreads();
        f16x8 af[2], bf[4];
        #pragma unroll
        for (int i = 0; i < 2; ++i)
            af[i] = *reinterpret_cast<const f16x8*>(Al + (wr + i * 16 + lrow) * 40 + lk);
        #pragma unroll
        for (int j = 0; j < 4; ++j)
            bf[j] = *reinterpret_cast<const f16x8*>(Bl + (j * 16 + lrow) * 40 + lk);
        #pragma unroll
        for (int i = 0; i < 2; ++i)
            #pragma unroll
            for (int j = 0; j < 4; ++j)
                acc[i][j] = __builtin_amdgcn_mfma_f32_16x16x32_f16(af[i], bf[j], acc[i][j], 0, 0, 0);
    }

    float bp2v = bp2[0];
    int orow_b = (lane >> 4) * 4;
    #pragma unroll
    for (int i = 0; i < 2; ++i) {
        #pragma unroll
        for (int q = 0; q < 4; ++q) {
            int row = row0 + wr + i * 16 + orow_b + q;
            float p = 0.f;
            #pragma unroll
            for (int j = 0; j < 4; ++j) {
                int col = j * 16 + lrow;
                float tv = fmaxf(acc[i][j][q] + bp1[col], 0.f);
                p += tv * Wp2[col];
            }
            p += __shfl_xor(p, 1); p += __shfl_xor(p, 2);
            p += __shfl_xor(p, 4); p += __shfl_xor(p, 8);
            if (lrow == 0 && row < N) out[row] = p + bp2v;
        }
    }
}

extern "C" void kernel_launch(void* const* d_in, const int* in_sizes, int n_in,
                              void* d_out, int out_size, void* d_ws, size_t ws_size,
                              hipStream_t stream)
{
    const float* x   = (const float*)d_in[0];
    const float* pk  = (const float*)d_in[1];
    const float* pp  = (const float*)d_in[2];
    const int*   ei  = (const int*)d_in[3];
    const float* W0  = (const float*)d_in[4];
    const float* b0  = (const float*)d_in[5];
    const float* W1  = (const float*)d_in[6];
    const float* b1  = (const float*)d_in[7];
    const float* W2  = (const float*)d_in[8];
    const float* b2  = (const float*)d_in[9];
    const float* g0  = (const float*)d_in[10];
    const float* be0 = (const float*)d_in[11];
    const float* g1  = (const float*)d_in[12];
    const float* be1 = (const float*)d_in[13];
    const float* g2  = (const float*)d_in[14];
    const float* be2 = (const float*)d_in[15];
    const float* Wg  = (const float*)d_in[16];
    const float* bg  = (const float*)d_in[17];
    const float* Wp1 = (const float*)d_in[18];
    const float* bp1 = (const float*)d_in[19];
    const float* Wp2 = (const float*)d_in[20];
    const float* bp2 = (const float*)d_in[21];
    float* out = (float*)d_out;

    int  N = in_sizes[0] / 128;
    long E = in_sizes[3] / 2;

    long Nal = ((long)N + 255) / 256 * 256;
    long Eal = (E + 255) / 256 * 256;
    float* fws     = (float*)d_ws;
    float* dis     = fws;                        // [Nal] f32
    int*   cnt     = (int*)(dis + Nal);          // [Nal]
    int*   off     = cnt + Nal;                  // [Nal+256]
    int*   bsum    = off + Nal + 256;            // [1024]
    int*   csr_src = bsum + 1024;                // [Eal]
    __half* M16    = (__half*)(csr_src + Eal);   // M'   fp16 [N,128]
    __half* GATE16 = M16 + (long)N * HID;        // gate fp16 [N,128]
    __half* H16    = GATE16 + (long)N * HID;     // h    fp16 [N,128]
    __half* H193   = H16 + (long)N * HID;        // fp16 [N,224]
    __half* WTg    = H193 + (long)N * 224;       // [128,224]
    __half* WT0    = WTg + 128 * 224;
    __half* WT1    = WT0 + 128 * 224;            // [128,128]
    __half* WT2    = WT1 + 128 * 128;
    __half* WTp1   = WT2 + 128 * 128;            // [64,128]

    int nbN    = (N + 255) / 256;
    int nbE    = (int)((E + 255) / 256);
    int nbTile = (N + 127) / 128;
    int nbRow  = (N + 3) / 4;
    int nbCv   = (int)(((long)N * 56 + 255) / 256);
    int nbT224 = (128 * 224 + 255) / 256;
    int nbT128 = (128 * 128 + 255) / 256;
    int nbTp1  = (64 * 128 + 255) / 256;

    // ---- CSR build ----
    zero_int_kernel<<<256, 256, 0, stream>>>(cnt, N);
    count_deg_kernel<<<nbE, 256, 0, stream>>>(ei, cnt, E);
    dis_kernel<<<nbN, 256, 0, stream>>>(cnt, dis, N);
    scan1_kernel<<<nbN, 256, 0, stream>>>(cnt, off, bsum, N);
    scan2_kernel<<<1, 1024, 0, stream>>>(bsum, nbN);
    scan3_kernel<<<nbN, 256, 0, stream>>>(off, bsum, N, (int)E);
    zero_int_kernel<<<256, 256, 0, stream>>>(cnt, N);
    fill_kernel<<<nbE, 256, 0, stream>>>(ei, off, cnt, csr_src, E);

    // ---- fp16 prep ----
    conv193_kernel<<<nbCv, 256, 0, stream>>>(x, pk, pp, H193, N);
    transpose_w_kernel<<<nbT224, 256, 0, stream>>>(Wg, WTg, 193, 224, 128);
    transpose_w_kernel<<<nbT224, 256, 0, stream>>>(W0, WT0, 193, 224, 128);
    transpose_w_kernel<<<nbT128, 256, 0, stream>>>(W1, WT1, 128, 128, 128);
    transpose_w_kernel<<<nbT128, 256, 0, stream>>>(W2, WT2, 128, 128, 128);
    transpose_w_kernel<<<nbTp1, 256, 0, stream>>>(Wp1, WTp1, 128, 128, 64);

    // ---- gate & layer 0 ----
    mfma_lin_kernel<224, 1><<<nbTile, 256, 0, stream>>>(H193, WTg, bg, nullptr, GATE16, N);
    mfma_lin_kernel<224, 0><<<nbTile, 256, 0, stream>>>(H193, WT0, nullptr, dis, M16, N);
    gcn16_kernel<0><<<nbRow, 256, 0, stream>>>(off, csr_src, dis, M16, b0, g0, be0, GATE16, H16, N);

    // ---- layer 1 ----
    mfma_lin_kernel<128, 0><<<nbTile, 256, 0, stream>>>(H16, WT1, nullptr, dis, M16, N);
    gcn16_kernel<1><<<nbRow, 256, 0, stream>>>(off, csr_src, dis, M16, b1, g1, be1, H16, H16, N);

    // ---- layer 2 ----
    mfma_lin_kernel<128, 0><<<nbTile, 256, 0, stream>>>(H16, WT2, nullptr, dis, M16, N);
    gcn16_kernel<1><<<nbRow, 256, 0, stream>>>(off, csr_src, dis, M16, b2, g2, be2, H16, H16, N);

    // ---- head ----
    head3_kernel<<<nbTile, 256, 0, stream>>>(H16, WTp1, bp1, Wp2, bp2, out, N);
}

// Round 16
// 695.999 us; speedup vs baseline: 1.0318x; 1.0318x over previous
//
#include <hip/hip_runtime.h>
#include <hip/hip_bf16.h>
#include <hip/hip_fp16.h>

#define HID 128

typedef _Float16 f16x8 __attribute__((ext_vector_type(8)));
typedef float f32x4 __attribute__((ext_vector_type(4)));

// ---------------- zero ----------------
__global__ __launch_bounds__(256)
void zero_int_kernel(int* __restrict__ p, long n) {
    long i = (long)blockIdx.x * 256 + threadIdx.x;
    long stride = (long)gridDim.x * 256;
    for (; i < n; i += stride) p[i] = 0;
}

// ---------------- degree count (int) ----------------
__global__ __launch_bounds__(256)
void count_deg_kernel(const int* __restrict__ ei, int* __restrict__ cnt, long E) {
    long e = (long)blockIdx.x * 256 + threadIdx.x;
    if (e < E) atomicAdd(&cnt[ei[E + e]], 1);
}

// ---------------- exclusive scan (3-phase); scan1 also emits dis ------------
__global__ __launch_bounds__(256)
void scan1_kernel(const int* __restrict__ cnt, int* __restrict__ off,
                  int* __restrict__ bsum, float* __restrict__ dis, int N) {
    __shared__ int sh[256];
    int i = blockIdx.x * 256 + threadIdx.x;
    int v = (i < N) ? cnt[i] : 0;
    if (i < N) dis[i] = rsqrtf(1.0f + (float)v);   // +1 self loop
    sh[threadIdx.x] = v;
    __syncthreads();
    for (int o = 1; o < 256; o <<= 1) {
        int t = 0;
        if (threadIdx.x >= o) t = sh[threadIdx.x - o];
        __syncthreads();
        if (threadIdx.x >= o) sh[threadIdx.x] += t;
        __syncthreads();
    }
    if (i < N) off[i] = sh[threadIdx.x] - v;
    if (threadIdx.x == 255) bsum[blockIdx.x] = sh[255];
}

__global__ __launch_bounds__(1024)
void scan2_kernel(int* __restrict__ bsum, int nb) {
    __shared__ int sh[1024];
    int t = threadIdx.x;
    int v = (t < nb) ? bsum[t] : 0;
    sh[t] = v;
    __syncthreads();
    for (int o = 1; o < 1024; o <<= 1) {
        int u = 0;
        if (t >= o) u = sh[t - o];
        __syncthreads();
        if (t >= o) sh[t] += u;
        __syncthreads();
    }
    if (t < nb) bsum[t] = sh[t] - v;
}

__global__ __launch_bounds__(256)
void scan3_kernel(int* __restrict__ off, const int* __restrict__ bsum, int N, int E) {
    int i = blockIdx.x * 256 + threadIdx.x;
    if (i < N) off[i] += bsum[blockIdx.x];
    if (i == 0) off[N] = E;
}

// ---------------- CSR fill (src index only — weight folded into M') --------
__global__ __launch_bounds__(256)
void fill_kernel(const int* __restrict__ ei, const int* __restrict__ off,
                 int* __restrict__ cnt, int* __restrict__ csr_src, long E) {
    long e = (long)blockIdx.x * 256 + threadIdx.x;
    if (e >= E) return;
    int s = ei[e], d = ei[E + e];
    int pos = off[d] + atomicAdd(&cnt[d], 1);
    csr_src[pos] = s;
}

// ------- batched weight transpose: all 5 weights in one launch --------------
// WTg/WT0: [128,224] from [193,128]; WT1/WT2: [128,128]; WTp1: [64,128] from [128,64]
__global__ __launch_bounds__(256)
void transpose_all_kernel(const float* __restrict__ Wg, const float* __restrict__ W0,
                          const float* __restrict__ W1, const float* __restrict__ W2,
                          const float* __restrict__ Wp1,
                          __half* __restrict__ WTg, __half* __restrict__ WT0,
                          __half* __restrict__ WT1, __half* __restrict__ WT2,
                          __half* __restrict__ WTp1)
{
    int i = blockIdx.x * 256 + threadIdx.x;
    if (i < 28672) {
        int c = i / 224, k = i - c * 224;
        WTg[i] = (k < 193) ? __float2half(Wg[(long)k * 128 + c]) : __half(0.f);
    } else if (i < 57344) {
        int j = i - 28672; int c = j / 224, k = j - c * 224;
        WT0[j] = (k < 193) ? __float2half(W0[(long)k * 128 + c]) : __half(0.f);
    } else if (i < 73728) {
        int j = i - 57344; int c = j / 128, k = j - c * 128;
        WT1[j] = __float2half(W1[(long)k * 128 + c]);
    } else if (i < 90112) {
        int j = i - 73728; int c = j / 128, k = j - c * 128;
        WT2[j] = __float2half(W2[(long)k * 128 + c]);
    } else if (i < 98304) {
        int j = i - 90112; int c = j / 128, k = j - c * 128;
        WTp1[j] = __float2half(Wp1[(long)k * 64 + c]);
    }
}

// ======== dual MFMA: gate = sigmoid(h193@Wg+bg), M0 = (h193@W0)*dis =========
// Reads fp32 x/pk/pp directly (fp16 convert in staging); one A pass, two B.
__global__ __launch_bounds__(256)
void mfma_dual224_kernel(const float* __restrict__ x, const float* __restrict__ pk,
                         const float* __restrict__ pp,
                         const __half* __restrict__ WTg, const __half* __restrict__ WT0,
                         const float* __restrict__ bg, const float* __restrict__ dis,
                         __half* __restrict__ gate_out, __half* __restrict__ m_out, int N)
{
    __shared__ __half Al[128 * 40];
    __shared__ __half Bg[128 * 40];
    __shared__ __half B0[128 * 40];
    int t = threadIdx.x;
    int w = t >> 6, lane = t & 63;
    int wr = (w & 1) * 64, wc = (w >> 1) * 64;
    int row0 = blockIdx.x * 128;
    int lrow = lane & 15, lk = (lane >> 4) * 8;

    f32x4 accg[4][4], acc0[4][4];
    #pragma unroll
    for (int i = 0; i < 4; ++i)
        #pragma unroll
        for (int j = 0; j < 4; ++j)
            #pragma unroll
            for (int q = 0; q < 4; ++q) { accg[i][j][q] = 0.f; acc0[i][j][q] = 0.f; }

    int sr = t >> 2, sp = t & 3;
    for (int ks = 0; ks < 7; ++ks) {
        if (ks) __syncthreads();
        // ---- stage A from fp32 sources (convert to fp16) ----
        #pragma unroll
        for (int hf = 0; hf < 2; ++hf) {
            int r_l = sr + hf * 64;
            int r = min(row0 + r_l, N - 1);
            int c0 = ks * 32 + sp * 8;
            __half tmp[8];
            if (ks < 4) {
                float4 a = *reinterpret_cast<const float4*>(x + (long)r * 128 + c0);
                float4 b = *reinterpret_cast<const float4*>(x + (long)r * 128 + c0 + 4);
                tmp[0] = __float2half(a.x); tmp[1] = __float2half(a.y);
                tmp[2] = __float2half(a.z); tmp[3] = __float2half(a.w);
                tmp[4] = __float2half(b.x); tmp[5] = __float2half(b.y);
                tmp[6] = __float2half(b.z); tmp[7] = __float2half(b.w);
            } else if (ks < 6) {
                float4 a = *reinterpret_cast<const float4*>(pk + (long)r * 64 + (c0 - 128));
                float4 b = *reinterpret_cast<const float4*>(pk + (long)r * 64 + (c0 - 128) + 4);
                tmp[0] = __float2half(a.x); tmp[1] = __float2half(a.y);
                tmp[2] = __float2half(a.z); tmp[3] = __float2half(a.w);
                tmp[4] = __float2half(b.x); tmp[5] = __float2half(b.y);
                tmp[6] = __float2half(b.z); tmp[7] = __float2half(b.w);
            } else {
                #pragma unroll
                for (int z = 0; z < 8; ++z) tmp[z] = __half(0.f);
                if (sp == 0) tmp[0] = __float2half(pp[r]);   // col 192
            }
            *reinterpret_cast<uint4*>(Al + r_l * 40 + sp * 8) = *reinterpret_cast<uint4*>(tmp);
        }
        // ---- stage both B panels ----
        {
            int c0 = ks * 32 + sp * 8;
            *reinterpret_cast<uint4*>(Bg + sr * 40 + sp * 8) =
                *reinterpret_cast<const uint4*>(WTg + (long)sr * 224 + c0);
            *reinterpret_cast<uint4*>(Bg + (sr + 64) * 40 + sp * 8) =
                *reinterpret_cast<const uint4*>(WTg + (long)(sr + 64) * 224 + c0);
            *reinterpret_cast<uint4*>(B0 + sr * 40 + sp * 8) =
                *reinterpret_cast<const uint4*>(WT0 + (long)sr * 224 + c0);
            *reinterpret_cast<uint4*>(B0 + (sr + 64) * 40 + sp * 8) =
                *reinterpret_cast<const uint4*>(WT0 + (long)(sr + 64) * 224 + c0);
        }
        __syncthreads();
        f16x8 af[4], bgf[4], b0f[4];
        #pragma unroll
        for (int i = 0; i < 4; ++i) {
            af[i]  = *reinterpret_cast<const f16x8*>(Al + (wr + i * 16 + lrow) * 40 + lk);
            bgf[i] = *reinterpret_cast<const f16x8*>(Bg + (wc + i * 16 + lrow) * 40 + lk);
            b0f[i] = *reinterpret_cast<const f16x8*>(B0 + (wc + i * 16 + lrow) * 40 + lk);
        }
        #pragma unroll
        for (int i = 0; i < 4; ++i)
            #pragma unroll
            for (int j = 0; j < 4; ++j) {
                accg[i][j] = __builtin_amdgcn_mfma_f32_16x16x32_f16(af[i], bgf[j], accg[i][j], 0, 0, 0);
                acc0[i][j] = __builtin_amdgcn_mfma_f32_16x16x32_f16(af[i], b0f[j], acc0[i][j], 0, 0, 0);
            }
    }

    int orow_b = (lane >> 4) * 4;
    #pragma unroll
    for (int i = 0; i < 4; ++i) {
        #pragma unroll
        for (int j = 0; j < 4; ++j) {
            int col = wc + j * 16 + lrow;
            #pragma unroll
            for (int q = 0; q < 4; ++q) {
                int row = row0 + wr + i * 16 + orow_b + q;
                if (row >= N) continue;
                float vg = accg[i][j][q] + bg[col];
                gate_out[(long)row * HID + col] = __float2half(1.f / (1.f + expf(-vg)));
                m_out[(long)row * HID + col]    = __float2half(acc0[i][j][q] * dis[row]);
            }
        }
    }
}

// ======== MFMA linear: out[N,128] = A16[N,128] @ W[128,128], fp16*dis out ===
template<int KP>
__global__ __launch_bounds__(256)
void mfma_lin_kernel(const __half* __restrict__ A16, const __half* __restrict__ WT,
                     const float* __restrict__ dis, __half* __restrict__ outp, int N)
{
    constexpr int NK = KP / 32;
    __shared__ __half Al[128 * 40];
    __shared__ __half Bl[128 * 40];
    int t = threadIdx.x;
    int w = t >> 6, lane = t & 63;
    int wr = (w & 1) * 64, wc = (w >> 1) * 64;
    int row0 = blockIdx.x * 128;
    int lrow = lane & 15, lk = (lane >> 4) * 8;

    f32x4 acc[4][4];
    #pragma unroll
    for (int i = 0; i < 4; ++i)
        #pragma unroll
        for (int j = 0; j < 4; ++j)
            #pragma unroll
            for (int q = 0; q < 4; ++q) acc[i][j][q] = 0.f;

    int sr = t >> 2, sp = t & 3;
    for (int ks = 0; ks < NK; ++ks) {
        if (ks) __syncthreads();
        {
            int rr  = min(row0 + sr, N - 1);
            int rr2 = min(row0 + sr + 64, N - 1);
            *reinterpret_cast<uint4*>(Al + sr * 40 + sp * 8) =
                *reinterpret_cast<const uint4*>(A16 + (long)rr * KP + ks * 32 + sp * 8);
            *reinterpret_cast<uint4*>(Al + (sr + 64) * 40 + sp * 8) =
                *reinterpret_cast<const uint4*>(A16 + (long)rr2 * KP + ks * 32 + sp * 8);
            *reinterpret_cast<uint4*>(Bl + sr * 40 + sp * 8) =
                *reinterpret_cast<const uint4*>(WT + (long)sr * KP + ks * 32 + sp * 8);
            *reinterpret_cast<uint4*>(Bl + (sr + 64) * 40 + sp * 8) =
                *reinterpret_cast<const uint4*>(WT + (long)(sr + 64) * KP + ks * 32 + sp * 8);
        }
        __syncthreads();
        f16x8 af[4], bf[4];
        #pragma unroll
        for (int i = 0; i < 4; ++i) {
            af[i] = *reinterpret_cast<const f16x8*>(Al + (wr + i * 16 + lrow) * 40 + lk);
            bf[i] = *reinterpret_cast<const f16x8*>(Bl + (wc + i * 16 + lrow) * 40 + lk);
        }
        #pragma unroll
        for (int i = 0; i < 4; ++i)
            #pragma unroll
            for (int j = 0; j < 4; ++j)
                acc[i][j] = __builtin_amdgcn_mfma_f32_16x16x32_f16(af[i], bf[j], acc[i][j], 0, 0, 0);
    }

    int orow_b = (lane >> 4) * 4;
    #pragma unroll
    for (int i = 0; i < 4; ++i) {
        #pragma unroll
        for (int j = 0; j < 4; ++j) {
            int col = wc + j * 16 + lrow;
            #pragma unroll
            for (int q = 0; q < 4; ++q) {
                int row = row0 + wr + i * 16 + orow_b + q;
                if (row >= N) continue;
                outp[(long)row * HID + col] = __float2half(acc[i][j][q] * dis[row]);
            }
        }
    }
}

// ------------- fused: fp16 CSR gather (pre-scaled M') + LN + relu + post ----
// v = dis[r] * (sum_e M'[src[e]] + M'[r]) + bias      (M' = dis*m)
// MODE 0: hout[r] = relu(LN(v)) * hin[r]  (hin = gate, fp16)
// MODE 1: hout[r] = hin[r] + relu(LN(v))  (hin == hout = h, fp16)
template<int MODE>
__global__ __launch_bounds__(256)
void gcn16_kernel(const int* __restrict__ off, const int* __restrict__ src,
                  const float* __restrict__ dis,
                  const __half* __restrict__ m16, const float* __restrict__ bias,
                  const float* __restrict__ g, const float* __restrict__ be,
                  const __half* __restrict__ hin, __half* __restrict__ hout, int N)
{
    int wave = threadIdx.x >> 6, lane = threadIdx.x & 63;
    int r = blockIdx.x * 4 + wave;
    if (r >= N) return;
    int beg = off[r], end = off[r + 1];
    float dr = dis[r];
    int c2 = lane << 1;
    float sx0 = 0.f, sy0 = 0.f, sx1 = 0.f, sy1 = 0.f;
    float sx2 = 0.f, sy2 = 0.f, sx3 = 0.f, sy3 = 0.f;
    int e = beg;
    for (; e + 8 <= end; e += 8) {
        int s0 = src[e],     s1 = src[e + 1], s2 = src[e + 2], s3 = src[e + 3];
        int s4 = src[e + 4], s5 = src[e + 5], s6 = src[e + 6], s7 = src[e + 7];
        __half2 h0 = *reinterpret_cast<const __half2*>(m16 + (long)s0 * HID + c2);
        __half2 h1 = *reinterpret_cast<const __half2*>(m16 + (long)s1 * HID + c2);
        __half2 h2 = *reinterpret_cast<const __half2*>(m16 + (long)s2 * HID + c2);
        __half2 h3 = *reinterpret_cast<const __half2*>(m16 + (long)s3 * HID + c2);
        __half2 h4 = *reinterpret_cast<const __half2*>(m16 + (long)s4 * HID + c2);
        __half2 h5 = *reinterpret_cast<const __half2*>(m16 + (long)s5 * HID + c2);
        __half2 h6 = *reinterpret_cast<const __half2*>(m16 + (long)s6 * HID + c2);
        __half2 h7 = *reinterpret_cast<const __half2*>(m16 + (long)s7 * HID + c2);
        float2 f0 = __half22float2(h0), f1 = __half22float2(h1);
        float2 f2 = __half22float2(h2), f3 = __half22float2(h3);
        float2 f4 = __half22float2(h4), f5 = __half22float2(h5);
        float2 f6 = __half22float2(h6), f7 = __half22float2(h7);
        sx0 += f0.x + f4.x; sy0 += f0.y + f4.y;
        sx1 += f1.x + f5.x; sy1 += f1.y + f5.y;
        sx2 += f2.x + f6.x; sy2 += f2.y + f6.y;
        sx3 += f3.x + f7.x; sy3 += f3.y + f7.y;
    }
    for (; e < end; ++e) {
        int s0 = src[e];
        float2 f0 = __half22float2(*reinterpret_cast<const __half2*>(m16 + (long)s0 * HID + c2));
        sx0 += f0.x; sy0 += f0.y;
    }
    float2 ms = __half22float2(*reinterpret_cast<const __half2*>(m16 + (long)r * HID + c2));
    const float2 bi = *reinterpret_cast<const float2*>(bias + c2);
    float vx = dr * ((sx0 + sx1) + (sx2 + sx3) + ms.x) + bi.x;
    float vy = dr * ((sy0 + sy1) + (sy2 + sy3) + ms.y) + bi.y;
    float s = vx + vy;
    for (int o = 32; o; o >>= 1) s += __shfl_xor(s, o);
    float mean = s * (1.f / 128.f);
    float qx = vx - mean, qy = vy - mean;
    float q = qx * qx + qy * qy;
    for (int o = 32; o; o >>= 1) q += __shfl_xor(q, o);
    float rs = rsqrtf(q * (1.f / 128.f) + 1e-5f);
    const float2 gg = *reinterpret_cast<const float2*>(g + c2);
    const float2 bb = *reinterpret_cast<const float2*>(be + c2);
    float y0 = fmaxf(qx * rs * gg.x + bb.x, 0.f);
    float y1 = fmaxf(qy * rs * gg.y + bb.y, 0.f);
    float2 hv = __half22float2(*reinterpret_cast<const __half2*>(hin + (long)r * HID + c2));
    float2 o2;
    if (MODE == 0) { o2.x = y0 * hv.x; o2.y = y1 * hv.y; }
    else           { o2.x = hv.x + y0; o2.y = hv.y + y1; }
    *reinterpret_cast<__half2*>(hout + (long)r * HID + c2) = __float22half2_rn(o2);
}

// ======== MFMA head: out[r] = relu(h16@Wp1+bp1) @ Wp2 + bp2 ================
__global__ __launch_bounds__(256)
void head3_kernel(const __half* __restrict__ h16, const __half* __restrict__ WTp1,
                  const float* __restrict__ bp1, const float* __restrict__ Wp2,
                  const float* __restrict__ bp2, float* __restrict__ out, int N)
{
    __shared__ __half Al[128 * 40];
    __shared__ __half Bl[64 * 40];
    int t = threadIdx.x;
    int w = t >> 6, lane = t & 63;
    int wr = w * 32;
    int row0 = blockIdx.x * 128;
    int lrow = lane & 15, lk = (lane >> 4) * 8;

    f32x4 acc[2][4];
    #pragma unroll
    for (int i = 0; i < 2; ++i)
        #pragma unroll
        for (int j = 0; j < 4; ++j)
            #pragma unroll
            for (int q = 0; q < 4; ++q) acc[i][j][q] = 0.f;

    int sr = t >> 2, sp = t & 3;
    for (int ks = 0; ks < 4; ++ks) {
        if (ks) __syncthreads();
        {
            int rr  = min(row0 + sr, N - 1);
            int rr2 = min(row0 + sr + 64, N - 1);
            *reinterpret_cast<uint4*>(Al + sr * 40 + sp * 8) =
                *reinterpret_cast<const uint4*>(h16 + (long)rr * HID + ks * 32 + sp * 8);
            *reinterpret_cast<uint4*>(Al + (sr + 64) * 40 + sp * 8) =
                *reinterpret_cast<const uint4*>(h16 + (long)rr2 * HID + ks * 32 + sp * 8);
            if (sr < 64)
                *reinterpret_cast<uint4*>(Bl + sr * 40 + sp * 8) =
                    *reinterpret_cast<const uint4*>(WTp1 + (long)sr * HID + ks * 32 + sp * 8);
        }
        __syncthreads();
        f16x8 af[2], bf[4];
        #pragma unroll
        for (int i = 0; i < 2; ++i)
            af[i] = *reinterpret_cast<const f16x8*>(Al + (wr + i * 16 + lrow) * 40 + lk);
        #pragma unroll
        for (int j = 0; j < 4; ++j)
            bf[j] = *reinterpret_cast<const f16x8*>(Bl + (j * 16 + lrow) * 40 + lk);
        #pragma unroll
        for (int i = 0; i < 2; ++i)
            #pragma unroll
            for (int j = 0; j < 4; ++j)
                acc[i][j] = __builtin_amdgcn_mfma_f32_16x16x32_f16(af[i], bf[j], acc[i][j], 0, 0, 0);
    }

    float bp2v = bp2[0];
    int orow_b = (lane >> 4) * 4;
    #pragma unroll
    for (int i = 0; i < 2; ++i) {
        #pragma unroll
        for (int q = 0; q < 4; ++q) {
            int row = row0 + wr + i * 16 + orow_b + q;
            float p = 0.f;
            #pragma unroll
            for (int j = 0; j < 4; ++j) {
                int col = j * 16 + lrow;
                float tv = fmaxf(acc[i][j][q] + bp1[col], 0.f);
                p += tv * Wp2[col];
            }
            p += __shfl_xor(p, 1); p += __shfl_xor(p, 2);
            p += __shfl_xor(p, 4); p += __shfl_xor(p, 8);
            if (lrow == 0 && row < N) out[row] = p + bp2v;
        }
    }
}

extern "C" void kernel_launch(void* const* d_in, const int* in_sizes, int n_in,
                              void* d_out, int out_size, void* d_ws, size_t ws_size,
                              hipStream_t stream)
{
    const float* x   = (const float*)d_in[0];
    const float* pk  = (const float*)d_in[1];
    const float* pp  = (const float*)d_in[2];
    const int*   ei  = (const int*)d_in[3];
    const float* W0  = (const float*)d_in[4];
    const float* b0  = (const float*)d_in[5];
    const float* W1  = (const float*)d_in[6];
    const float* b1  = (const float*)d_in[7];
    const float* W2  = (const float*)d_in[8];
    const float* b2  = (const float*)d_in[9];
    const float* g0  = (const float*)d_in[10];
    const float* be0 = (const float*)d_in[11];
    const float* g1  = (const float*)d_in[12];
    const float* be1 = (const float*)d_in[13];
    const float* g2  = (const float*)d_in[14];
    const float* be2 = (const float*)d_in[15];
    const float* Wg  = (const float*)d_in[16];
    const float* bg  = (const float*)d_in[17];
    const float* Wp1 = (const float*)d_in[18];
    const float* bp1 = (const float*)d_in[19];
    const float* Wp2 = (const float*)d_in[20];
    const float* bp2 = (const float*)d_in[21];
    float* out = (float*)d_out;

    int  N = in_sizes[0] / 128;
    long E = in_sizes[3] / 2;

    long Nal = ((long)N + 255) / 256 * 256;
    long Eal = (E + 255) / 256 * 256;
    float* fws     = (float*)d_ws;
    float* dis     = fws;                        // [Nal] f32
    int*   cnt     = (int*)(dis + Nal);          // [Nal]
    int*   off     = cnt + Nal;                  // [Nal+256]
    int*   bsum    = off + Nal + 256;            // [1024]
    int*   csr_src = bsum + 1024;                // [Eal]
    __half* M16    = (__half*)(csr_src + Eal);   // M'   fp16 [N,128]
    __half* GATE16 = M16 + (long)N * HID;        // gate fp16 [N,128]
    __half* H16    = GATE16 + (long)N * HID;     // h    fp16 [N,128]
    __half* WTg    = H16 + (long)N * HID;        // [128,224]
    __half* WT0    = WTg + 128 * 224;
    __half* WT1    = WT0 + 128 * 224;            // [128,128]
    __half* WT2    = WT1 + 128 * 128;
    __half* WTp1   = WT2 + 128 * 128;            // [64,128]

    int nbN    = (N + 255) / 256;
    int nbE    = (int)((E + 255) / 256);
    int nbTile = (N + 127) / 128;
    int nbRow  = (N + 3) / 4;
    int nbTrs  = (98304 + 255) / 256;

    // ---- CSR build ----
    zero_int_kernel<<<256, 256, 0, stream>>>(cnt, N);
    count_deg_kernel<<<nbE, 256, 0, stream>>>(ei, cnt, E);
    scan1_kernel<<<nbN, 256, 0, stream>>>(cnt, off, bsum, dis, N);
    scan2_kernel<<<1, 1024, 0, stream>>>(bsum, nbN);
    scan3_kernel<<<nbN, 256, 0, stream>>>(off, bsum, N, (int)E);
    zero_int_kernel<<<256, 256, 0, stream>>>(cnt, N);
    fill_kernel<<<nbE, 256, 0, stream>>>(ei, off, cnt, csr_src, E);

    // ---- fp16 weight prep (single launch) ----
    transpose_all_kernel<<<nbTrs, 256, 0, stream>>>(Wg, W0, W1, W2, Wp1,
                                                    WTg, WT0, WT1, WT2, WTp1);

    // ---- gate & layer 0 (fused dual pass over fp32 inputs) ----
    mfma_dual224_kernel<<<nbTile, 256, 0, stream>>>(x, pk, pp, WTg, WT0, bg, dis,
                                                    GATE16, M16, N);
    gcn16_kernel<0><<<nbRow, 256, 0, stream>>>(off, csr_src, dis, M16, b0, g0, be0, GATE16, H16, N);

    // ---- layer 1 ----
    mfma_lin_kernel<128><<<nbTile, 256, 0, stream>>>(H16, WT1, dis, M16, N);
    gcn16_kernel<1><<<nbRow, 256, 0, stream>>>(off, csr_src, dis, M16, b1, g1, be1, H16, H16, N);

    // ---- layer 2 ----
    mfma_lin_kernel<128><<<nbTile, 256, 0, stream>>>(H16, WT2, dis, M16, N);
    gcn16_kernel<1><<<nbRow, 256, 0, stream>>>(off, csr_src, dis, M16, b2, g2, be2, H16, H16, N);

    // ---- head ----
    head3_kernel<<<nbTile, 256, 0, stream>>>(H16, WTp1, bp1, Wp2, bp2, out, N);
}